// Round 4
// baseline (1839.263 us; speedup 1.0000x reference)
//
#include <hip/hip_runtime.h>
#include <cstddef>

typedef short short8 __attribute__((ext_vector_type(8)));
typedef float f32x4 __attribute__((ext_vector_type(4)));
typedef unsigned short u16;

// problem dims
#define Bn 512
#define Tn 64
#define En 1024
#define An 32
#define Sn 30
#define Dn 200
#define SSn 230
#define OUTC 380

// packed weight regions, u16 element offsets inside d_ws
#define U16_WINP0  0
#define U16_WINPCA 6656
#define U16_WGRU   66560
#define U16_WIMG   326144
#define U16_WOBSD  372736
#define U16_WIMS   419328
#define U16_WOBSS  433664
#define U16_WOBSE  448000
#define U16_PREO   660992      // pre_obs bf16 [T*B,200]  (b_obs folded)
#define U16_PREI   7214592     // pre_inp bf16 [T*B,200]  (b_inp folded)

// short8 indices (u16/8)
#define WINP0_8  0
#define WINPCA_8 832
#define WGRU_8   8320
#define WIMG_8   40768
#define WOBSD_8  46592
#define WIMS_8   52416
#define WOBSS_8  54208
#define WOBSE_8  56000

#define DEV static __device__ __forceinline__
#define MFMA(a,b,c) __builtin_amdgcn_mfma_f32_16x16x32_bf16((a),(b),(c),0,0,0)

DEV u16 f2bf(float f) {
  union { float f; unsigned u; } v; v.f = f;
  return (u16)((v.u + 0x7FFFu + ((v.u >> 16) & 1u)) >> 16);
}
DEV float bf2f(u16 h) {
  union { unsigned u; float f; } v; v.u = ((unsigned)h) << 16; return v.f;
}
// fast native transcendentals (v_exp_f32 / v_log_f32 / v_rcp_f32)
DEV float fexp(float x)  { return __builtin_amdgcn_exp2f(x * 1.44269504f); }
DEV float sigm(float x)  { return __builtin_amdgcn_rcpf(1.f + fexp(-x)); }
DEV float tanhf_(float x){ return 1.f - 2.f * __builtin_amdgcn_rcpf(fexp(2.f * x) + 1.f); }
DEV float elu1(float x)  { return x > 0.f ? x : fexp(x) - 1.f; }
DEV float splus(float x) { return 0.69314718f * __builtin_amdgcn_logf(1.f + fexp(x)); }

// LDS-only barrier: drains ds ops (cross-wave LDS visibility) but leaves
// global loads/stores in flight across the barrier. v4: compute waves issue
// ONLY global loads, writer waves issue (almost) only stores -> no wave ever
// has a load-wait queued behind a store in its in-order vmcnt window.
DEV void barx() {
  asm volatile("s_waitcnt lgkmcnt(0)" ::: "memory");
  __builtin_amdgcn_s_barrier();
  asm volatile("" ::: "memory");
}

// ---------------------------------------------------------------- pack kernel
// One block per (region, nt) strip; LDS-staged, coalesced reads along rows.
// B-fragment order: frag (nt*KT+kt): el[lane*8+j] = W[kt*32+(lane>>4)*8+j][nt*16+(lane&15)]
__global__ __launch_bounds__(256) void k_pack2(
    const float* __restrict__ w_inp, const float* __restrict__ w_gru,
    const float* __restrict__ w_img, const float* __restrict__ w_obs,
    const float* __restrict__ w_ims, const float* __restrict__ w_obss,
    u16* __restrict__ ws) {
  int s = blockIdx.x;
  const float* src; int KT, Kr, ldN, roff, colbase, cmax; size_t dstbase; int ntKT;
  if (s < 13)      { src=w_inp;  KT=1;  Kr=30;   ldN=200; roff=0;   int nt=s;    colbase=nt*16; cmax=min(16,200-colbase); dstbase=U16_WINP0;  ntKT=nt*KT; }
  else if (s < 26) { src=w_inp;  KT=9;  Kr=262;  ldN=200; roff=30;  int nt=s-13; colbase=nt*16; cmax=min(16,200-colbase); dstbase=U16_WINPCA; ntKT=nt*KT; }
  else if (s < 65) { src=w_gru;  KT=13; Kr=400;  ldN=600; roff=0;   int ntp=s-26; int g=ntp/3, p=ntp%3;
                     colbase=p*200+g*16; cmax=min(16,200-g*16); dstbase=U16_WGRU; ntKT=ntp*KT; }
  else if (s < 78) { src=w_img;  KT=7;  Kr=200;  ldN=200; roff=0;   int nt=s-65; colbase=nt*16; cmax=min(16,200-colbase); dstbase=U16_WIMG;  ntKT=nt*KT; }
  else if (s < 91) { src=w_obs;  KT=7;  Kr=200;  ldN=200; roff=0;   int nt=s-78; colbase=nt*16; cmax=min(16,200-colbase); dstbase=U16_WOBSD; ntKT=nt*KT; }
  else if (s < 95) { src=w_ims;  KT=7;  Kr=200;  ldN=60;  roff=0;   int nt=s-91; colbase=nt*16; cmax=min(16,60-colbase);  dstbase=U16_WIMS;  ntKT=nt*KT; }
  else if (s < 99) { src=w_obss; KT=7;  Kr=200;  ldN=60;  roff=0;   int nt=s-95; colbase=nt*16; cmax=min(16,60-colbase);  dstbase=U16_WOBSS; ntKT=nt*KT; }
  else             { src=w_obs;  KT=32; Kr=1024; ldN=200; roff=200; int nt=s-99; colbase=nt*16; cmax=min(16,200-colbase); dstbase=U16_WOBSE; ntKT=nt*KT; }

  __shared__ float Ws[2048];       // 128 k-rows x 16 cols
  int tid = threadIdx.x;
  int nchunk = (KT + 3) >> 2;
  for (int kc = 0; kc < nchunk; ++kc) {
    __syncthreads();
    for (int i = tid; i < 2048; i += 256) {
      int r = i >> 4, c = i & 15;
      int k = kc * 128 + r;
      Ws[i] = (k < Kr && c < cmax) ? src[(size_t)(roff + k) * ldN + colbase + c] : 0.f;
    }
    __syncthreads();
    int nf = KT - kc * 4; if (nf > 4) nf = 4;
    int fi = tid >> 6, lane = tid & 63;
    if (fi < nf) {
      int kt = kc * 4 + fi;
      union { u16 h[8]; short8 v; } pk;
#pragma unroll
      for (int j = 0; j < 8; ++j)
        pk.h[j] = f2bf(Ws[(fi * 32 + ((lane >> 4) << 3) + j) * 16 + (lane & 15)]);
      *(short8*)&ws[dstbase + (size_t)(ntKT + kt) * 512 + lane * 8] = pk.v;
    }
  }
}

// ---------------------------------------------------------------- pre kernel
// pre_obs[t*512+b][n] = emb[b][t][:]@Wobse + b_obs    (bf16)
// pre_inp[t*512+b][n] = [ctx|act][b][t][:]@Winpca + b_inp  (bf16)
__global__ __launch_bounds__(256) void k_pre(
    const float* __restrict__ emb, const float* __restrict__ ctx,
    const float* __restrict__ act, const float* __restrict__ b_obs,
    const float* __restrict__ b_inp, u16* __restrict__ ws) {
  __shared__ u16 Asm[64 * 72];
  __shared__ short8 Bsm[26 * 64];
  const short8* Wb = (const short8*)ws;
  u16* preO = ws + U16_PREO;
  u16* preI = ws + U16_PREI;

  int tid = threadIdx.x, wv = tid >> 6, lane = tid & 63;
  int lrow = lane & 15, quad = lane >> 4;
  int m0 = blockIdx.x * 64;
  int t = m0 >> 9, b0 = m0 & 511;

  const f32x4 z4 = {0.f, 0.f, 0.f, 0.f};
  f32x4 acc[13];

  // ---------------- job 1: obs (K=1024 from emb)
#pragma unroll
  for (int i = 0; i < 13; ++i) acc[i] = z4;
  for (int kc = 0; kc < 16; ++kc) {
    __syncthreads();
#pragma unroll
    for (int q = 0; q < 4; ++q) {
      int i = tid + q * 256;
      int row = i >> 4, c4 = i & 15;
      const float* src = emb + ((size_t)((b0 + row) * Tn + t)) * En + kc * 64 + c4 * 4;
      float4 v = *(const float4*)src;
      union { u16 h[4]; unsigned long long ll; } p;
      p.h[0] = f2bf(v.x); p.h[1] = f2bf(v.y); p.h[2] = f2bf(v.z); p.h[3] = f2bf(v.w);
      *(unsigned long long*)&Asm[row * 72 + c4 * 4] = p.ll;
    }
    for (int q = 0; q < 7; ++q) {
      int i = tid + q * 256;
      if (i < 1664) {
        int pair = i >> 6, l = i & 63;
        int ktl = pair / 13, nt = pair % 13;
        Bsm[i] = Wb[WOBSE_8 + (size_t)(nt * 32 + kc * 2 + ktl) * 64 + l];
      }
    }
    __syncthreads();
#pragma unroll
    for (int ktl = 0; ktl < 2; ++ktl) {
      short8 a = *(const short8*)&Asm[(wv * 16 + lrow) * 72 + ktl * 32 + quad * 8];
#pragma unroll
      for (int nt = 0; nt < 13; ++nt)
        acc[nt] = MFMA(a, Bsm[(ktl * 13 + nt) * 64 + lane], acc[nt]);
    }
  }
#pragma unroll
  for (int nt = 0; nt < 13; ++nt) {
    int col = nt * 16 + lrow;
    if (col < 200) {
      float bias = b_obs[col];
#pragma unroll
      for (int r = 0; r < 4; ++r) {
        int m = t * 512 + b0 + wv * 16 + quad * 4 + r;
        preO[(size_t)m * 200 + col] = f2bf(acc[nt][r] + bias);
      }
    }
  }

  // ---------------- job 2: inp (K=262 from [ctx|act])
#pragma unroll
  for (int i = 0; i < 13; ++i) acc[i] = z4;
  for (int kc = 0; kc < 5; ++kc) {
    __syncthreads();
#pragma unroll
    for (int q = 0; q < 4; ++q) {
      int i = tid + q * 256;
      int row = i >> 4, c4 = i & 15;
      union { u16 h[4]; unsigned long long ll; } p;
#pragma unroll
      for (int e = 0; e < 4; ++e) {
        int k = kc * 64 + c4 * 4 + e;
        float v = 0.f;
        if (k < 230)      v = ctx[((size_t)(b0 + row) * Tn + t) * SSn + k];
        else if (k < 262) v = act[((size_t)(b0 + row) * Tn + t) * An + (k - 230)];
        p.h[e] = f2bf(v);
      }
      *(unsigned long long*)&Asm[row * 72 + c4 * 4] = p.ll;
    }
    int nktl = (kc < 4) ? 2 : 1;
    for (int q = 0; q < 7; ++q) {
      int i = tid + q * 256;
      if (i < nktl * 13 * 64) {
        int pair = i >> 6, l = i & 63;
        int ktl = pair / 13, nt = pair % 13;
        Bsm[i] = Wb[WINPCA_8 + (size_t)(nt * 9 + kc * 2 + ktl) * 64 + l];
      }
    }
    __syncthreads();
    for (int ktl = 0; ktl < nktl; ++ktl) {
      short8 a = *(const short8*)&Asm[(wv * 16 + lrow) * 72 + ktl * 32 + quad * 8];
#pragma unroll
      for (int nt = 0; nt < 13; ++nt)
        acc[nt] = MFMA(a, Bsm[(ktl * 13 + nt) * 64 + lane], acc[nt]);
    }
  }
#pragma unroll
  for (int nt = 0; nt < 13; ++nt) {
    int col = nt * 16 + lrow;
    if (col < 200) {
      float bias = b_inp[col];
#pragma unroll
      for (int r = 0; r < 4; ++r) {
        int m = t * 512 + b0 + wv * 16 + quad * 4 + r;
        preI[(size_t)m * 200 + col] = f2bf(acc[nt][r] + bias);
      }
    }
  }
}

// ---------------------------------------------------------------- scan kernel
// 32 blocks x 640 threads (10 waves); block owns 16 batch rows, 64 steps.
// v4: producer/consumer wave specialization.
//   waves 0-7 (compute): A/B/C/D pipeline; ONLY global loads, never stores.
//     Stage B forwards fp32 deter through detF (LDS); no epilogue work.
//   waves 8-9 (writers): copy detF->out after B3; posterior-stats epilogue
//     (om/os/ost + Uin) after B5; all NT stores live here, with a full step
//     of slack, never blocking a compute wave's vmcnt.
//   Wobsd LDS-resident (stage C ds_read-only), Wobss register-resident.
__global__ __launch_bounds__(640, 1) void k_scan(
    const float* __restrict__ g_no, const float* __restrict__ b_gru,
    const float* __restrict__ b_obss, const u16* __restrict__ ws,
    float* __restrict__ out) {

  // AB row layout (u16, stride 872): parity p at p*424: [x 0..199 | deter 200..423]
  __shared__ u16 AB[16 * 872];
  __shared__ u16 Uin[16 * 40];      // stoch (cols 0..29; 30,31 multiply zero B rows)
  __shared__ u16 hoA[16 * 232];     // ho; cols 200..231 MUST stay zero (K-pads)
  __shared__ u16 WdL[91 * 512];     // Wobsd: 91 B-fragments, LDS-resident
  __shared__ float detF[16 * 200];  // fp32 deter_new (exact value for out)

  const short8* Wb = (const short8*)ws;
  const u16* preO = ws + U16_PREO;
  const u16* preI = ws + U16_PREI;

  const int tid = threadIdx.x, wv = tid >> 6, lane = tid & 63;
  const int lrow = lane & 15, quad = lane >> 4;
  const int b0 = blockIdx.x * 16;
  const f32x4 z4 = {0.f, 0.f, 0.f, 0.f};
  const bool comp = wv < 8;
  const int wtid = tid - 512;            // writer lane id 0..127 (waves 8,9)

  // compute roles
  const bool two = wv < 5;               // waves 0-4 take a second tile (idx wv+8)
  const int g1 = (comp && two) ? (wv + 8) : wv;
  const int colA0 = wv * 16 + lrow;      // waves 8,9 don't use
  const int colA1 = g1 * 16 + lrow;
  const int dcol0 = colA0;
  const int dcol1 = colA1;

  // park stage-A fragments (harmless dummy for writers)
  const int wvc = comp ? wv : 0;
  short8 fA0 = Wb[WINP0_8 + (size_t)wvc * 64 + lane];
  short8 fA1 = Wb[WINP0_8 + (size_t)(comp ? g1 : 0) * 64 + lane];

  // per-role biases (update bias -1 folded into bgu)
  const int dc0s = comp ? dcol0 : 0;
  float bgr0 = b_gru[dc0s], bgc0 = b_gru[200 + dc0s], bgu0 = b_gru[400 + dc0s] - 1.f;
  float bgr1 = 0.f, bgc1 = 0.f, bgu1 = -1.f;
  if (comp && two && dcol1 < 200) { bgr1 = b_gru[dcol1]; bgc1 = b_gru[200 + dcol1]; bgu1 = b_gru[400 + dcol1] - 1.f; }
  const int cD = (wv & 3) * 16 + lrow;
  const float bD = (comp && wv < 4 && cD < 60) ? b_obss[cD] : 0.f;

  // loop-invariant weight pointers (GRU streams from L2)
  const short8* pr0 = Wb + WGRU_8 + (size_t)((3 * wvc + 0) * 13) * 64 + lane;
  const short8* pc0 = Wb + WGRU_8 + (size_t)((3 * wvc + 1) * 13) * 64 + lane;
  const short8* pu0 = Wb + WGRU_8 + (size_t)((3 * wvc + 2) * 13) * 64 + lane;
  const short8* pr1 = Wb + WGRU_8 + (size_t)((3 * g1 + 0) * 13) * 64 + lane;
  const short8* pc1 = Wb + WGRU_8 + (size_t)((3 * g1 + 1) * 13) * 64 + lane;
  const short8* pu1 = Wb + WGRU_8 + (size_t)((3 * g1 + 2) * 13) * 64 + lane;
  const short8* bpD = Wb + WOBSS_8 + (size_t)(((comp && wv < 4) ? wv : 0) * 7) * 64 + lane;

  // Wobss 7 frags (28 VGPR) -> stage D memory-free
  short8 wD[7];
#pragma unroll
  for (int k = 0; k < 7; ++k) wD[k] = bpD[k * 64];

  // stage Wobsd -> LDS (once; 91 KiB, coalesced 16B copies)
  {
    short8* Wl = (short8*)WdL;
    for (int i = tid; i < 91 * 64; i += 640) Wl[i] = Wb[WOBSD_8 + i];
  }

  // zero init ALL carry/pad regions (NaN-safety: MFMA propagates NaN*0)
  for (int i = tid; i < 16 * 872; i += 640) AB[i] = 0;
  for (int i = tid; i < 16 * 40; i += 640) Uin[i] = 0;
  for (int i = tid; i < 16 * 232; i += 640) hoA[i] = 0;
  __syncthreads();

  // sto overlay: f32 view of AB; step t's sto lives in the idle-parity x-region
  float* stoF = (float*)AB;        // row stride 436 floats

  // prefetch step 0 inputs
  u16 pinC0[4], pinC1[4] = {0,0,0,0}, pobC0[4], pobC1[4] = {0,0,0,0};
  float vnoW[4] = {0.f,0.f,0.f,0.f};     // writers' noise for current step
  if (comp) {
    size_t mb = (size_t)b0 + quad * 4;
#pragma unroll
    for (int r = 0; r < 4; ++r) pinC0[r] = preI[(mb + r) * 200 + colA0];
#pragma unroll
    for (int r = 0; r < 4; ++r) pobC0[r] = preO[(mb + r) * 200 + colA0];
    if (two && colA1 < 200) {
#pragma unroll
      for (int r = 0; r < 4; ++r) pinC1[r] = preI[(mb + r) * 200 + colA1];
#pragma unroll
      for (int r = 0; r < 4; ++r) pobC1[r] = preO[(mb + r) * 200 + colA1];
    }
  } else {
#pragma unroll
    for (int k = 0; k < 4; ++k) {
      int item = wtid + k * 128;
      if (item < 480) vnoW[k] = g_no[((size_t)b0 + item / 30) * Sn + item % 30];
    }
  }

  for (int t = 0; t < Tn; ++t) {
    const int par = t & 1;
    const int pb = par * 424, qb = 424 - pb;
    const int qbf = qb >> 1;               // sto float offset this step

    barx();   // B1: Uin stoch ready (epilogue of t-1)

    u16 pinN0[4], pinN1[4] = {0,0,0,0}, pobN0[4], pobN1[4] = {0,0,0,0};
    float vnoN[4] = {0.f,0.f,0.f,0.f};

    if (comp) {
      // ---- stage A: x = elu(stoch @ W0 + pre_inp)   [no global stores]
      short8 aU = *(const short8*)&Uin[lrow * 40 + quad * 8];
      f32x4 a0 = MFMA(aU, fA0, z4);
#pragma unroll
      for (int r = 0; r < 4; ++r)
        AB[(quad * 4 + r) * 872 + pb + colA0] = f2bf(elu1(a0[r] + bf2f(pinC0[r])));
      if (two) {
        f32x4 a1 = MFMA(aU, fA1, z4);
        if (colA1 < 200) {
#pragma unroll
          for (int r = 0; r < 4; ++r)
            AB[(quad * 4 + r) * 872 + pb + colA1] = f2bf(elu1(a1[r] + bf2f(pinC1[r])));
        }
      }
      // ---- prefetch inputs for step t+1 (loads only; fly across barriers)
      int tn = (t + 1 < Tn) ? (t + 1) : t;
      size_t mb = (size_t)tn * 512 + b0 + quad * 4;
#pragma unroll
      for (int r = 0; r < 4; ++r) pinN0[r] = preI[(mb + r) * 200 + colA0];
#pragma unroll
      for (int r = 0; r < 4; ++r) pobN0[r] = preO[(mb + r) * 200 + colA0];
      if (two && colA1 < 200) {
#pragma unroll
        for (int r = 0; r < 4; ++r) pinN1[r] = preI[(mb + r) * 200 + colA1];
#pragma unroll
        for (int r = 0; r < 4; ++r) pobN1[r] = preO[(mb + r) * 200 + colA1];
      }
    } else {
      // writers: prefetch next step's noise
      int tn = (t + 1 < Tn) ? (t + 1) : t;
#pragma unroll
      for (int k = 0; k < 4; ++k) {
        int item = wtid + k * 128;
        if (item < 480) vnoN[k] = g_no[((size_t)tn * 512 + b0 + item / 30) * Sn + item % 30];
      }
    }

    barx();   // B2: x ready

    if (comp) {
      // ---- stage B: gates + fused GRU; deter_new -> AB(parity^1) + detF(fp32)
      short8 ax[13];
#pragma unroll
      for (int kt = 0; kt < 13; ++kt)
        ax[kt] = *(const short8*)&AB[lrow * 872 + pb + kt * 32 + quad * 8];
      f32x4 ar0 = z4, ac0 = z4, au0 = z4, ar1 = z4, ac1 = z4, au1 = z4;
      if (two) {
#pragma unroll
        for (int kt = 0; kt < 13; ++kt) {   // 6 interleaved chains
          ar0 = MFMA(ax[kt], pr0[kt * 64], ar0);
          ar1 = MFMA(ax[kt], pr1[kt * 64], ar1);
          ac0 = MFMA(ax[kt], pc0[kt * 64], ac0);
          ac1 = MFMA(ax[kt], pc1[kt * 64], ac1);
          au0 = MFMA(ax[kt], pu0[kt * 64], au0);
          au1 = MFMA(ax[kt], pu1[kt * 64], au1);
        }
      } else {
#pragma unroll
        for (int kt = 0; kt < 13; ++kt) {
          ar0 = MFMA(ax[kt], pr0[kt * 64], ar0);
          ac0 = MFMA(ax[kt], pc0[kt * 64], ac0);
          au0 = MFMA(ax[kt], pu0[kt * 64], au0);
        }
      }
#pragma unroll
      for (int r = 0; r < 4; ++r) {
        int row = quad * 4 + r;
        float dold = bf2f(AB[row * 872 + pb + 200 + dcol0]);
        float rs = sigm(ar0[r] + bgr0);
        float cnd = tanhf_(rs * (ac0[r] + bgc0));
        float up = sigm(au0[r] + bgu0);
        float dn = up * cnd + (1.f - up) * dold;
        AB[row * 872 + qb + 200 + dcol0] = f2bf(dn);
        detF[row * 200 + dcol0] = dn;
      }
      if (two && dcol1 < 200) {
#pragma unroll
        for (int r = 0; r < 4; ++r) {
          int row = quad * 4 + r;
          float dold = bf2f(AB[row * 872 + pb + 200 + dcol1]);
          float rs = sigm(ar1[r] + bgr1);
          float cnd = tanhf_(rs * (ac1[r] + bgc1));
          float up = sigm(au1[r] + bgu1);
          float dn = up * cnd + (1.f - up) * dold;
          AB[row * 872 + qb + 200 + dcol1] = f2bf(dn);
          detF[row * 200 + dcol1] = dn;
        }
      }
    }

    barx();   // B3: deter_new ready (AB bf16 + detF fp32)

    if (comp) {
      // ---- stage C: ho = elu(deter_new @ Wobsd + pre_obs)   [LDS weights only]
      short8 ad[7];
#pragma unroll
      for (int kt = 0; kt < 7; ++kt)
        ad[kt] = *(const short8*)&AB[lrow * 872 + qb + 200 + kt * 32 + quad * 8];
      f32x4 h0 = z4, h1 = z4;
      if (two) {
#pragma unroll
        for (int kt = 0; kt < 7; ++kt) {
          h0 = MFMA(ad[kt], *(const short8*)&WdL[(wv * 7 + kt) * 512 + lane * 8], h0);
          h1 = MFMA(ad[kt], *(const short8*)&WdL[(g1 * 7 + kt) * 512 + lane * 8], h1);
        }
      } else {
#pragma unroll
        for (int kt = 0; kt < 7; ++kt)
          h0 = MFMA(ad[kt], *(const short8*)&WdL[(wv * 7 + kt) * 512 + lane * 8], h0);
      }
#pragma unroll
      for (int r = 0; r < 4; ++r)
        hoA[(quad * 4 + r) * 232 + colA0] = f2bf(elu1(h0[r] + bf2f(pobC0[r])));
      if (two && colA1 < 200) {
#pragma unroll
        for (int r = 0; r < 4; ++r)
          hoA[(quad * 4 + r) * 232 + colA1] = f2bf(elu1(h1[r] + bf2f(pobC1[r])));
      }
    } else {
      // ---- writers: deter -> out (fp32 exact, coalesced NT stores)
#pragma unroll
      for (int k = 0; k < 25; ++k) {
        int item = wtid + k * 128;          // 16*200 = 3200 = 25*128
        int row = item / 200, col = item - row * 200;
        float dn = detF[row * 200 + col];
        __builtin_nontemporal_store(dn, &out[((size_t)(b0 + row) * Tn + t) * OUTC + 180 + col]);
      }
    }

    barx();   // B4: ho ready

    if (comp && wv < 4) {
      // ---- stage D: so = ho @ Wobss + b  (waves 0-3) [register weights only]
      f32x4 acc = z4;
#pragma unroll
      for (int kt = 0; kt < 7; ++kt) {
        short8 a = *(const short8*)&hoA[lrow * 232 + kt * 32 + quad * 8];
        acc = MFMA(a, wD[kt], acc);
      }
      if (cD < 60) {
#pragma unroll
        for (int r = 0; r < 4; ++r)
          stoF[(quad * 4 + r) * 436 + qbf + cD] = acc[r] + bD;
      }
    }

    barx();   // B5: so ready

    if (!comp) {
      // ---- writers: posterior stats epilogue + next stoch
#pragma unroll
      for (int k = 0; k < 4; ++k) {
        int item = wtid + k * 128;
        if (item < 480) {
          int nrow = item / 30, ns = item - nrow * 30;
          size_t ob = ((size_t)(b0 + nrow) * Tn + t) * OUTC;
          float om = stoF[nrow * 436 + qbf + ns];
          float os = splus(stoF[nrow * 436 + qbf + 30 + ns]) + 0.1f;
          float ost = om + os * vnoW[k];
          __builtin_nontemporal_store(om,  &out[ob + ns]);
          __builtin_nontemporal_store(os,  &out[ob + 30 + ns]);
          __builtin_nontemporal_store(ost, &out[ob + 60 + ns]);
          Uin[nrow * 40 + ns] = f2bf(ost);
        }
      }
    }

    // rotate prefetch registers
    if (comp) {
#pragma unroll
      for (int r = 0; r < 4; ++r) {
        pinC0[r] = pinN0[r]; pinC1[r] = pinN1[r];
        pobC0[r] = pobN0[r]; pobC1[r] = pobN1[r];
      }
    } else {
#pragma unroll
      for (int k = 0; k < 4; ++k) vnoW[k] = vnoN[k];
    }
    // loop-top B1 guards Uin/A-region/sto-overlay reuse
  }
}

// ---------------------------------------------------------------- prior kernel
// Wide post-pass: h = elu(deter@Wimg+b), st = h@Wims+b, pm/ps/pst -> out[90..180)
__global__ __launch_bounds__(256) void k_prior(
    const float* __restrict__ g_np, const float* __restrict__ b_img,
    const float* __restrict__ b_ims, const u16* __restrict__ ws,
    float* __restrict__ out) {
  __shared__ u16 Ad[64 * 232];
  __shared__ u16 Ah[64 * 232];
  __shared__ float stf[64 * 66];
  const short8* Wb = (const short8*)ws;

  int tid = threadIdx.x, wv = tid >> 6, lane = tid & 63;
  int lrow = lane & 15, quad = lane >> 4;
  int b = blockIdx.x;                 // 64 rows = all t for batch row b
  const f32x4 z4 = {0.f, 0.f, 0.f, 0.f};

  // zero-init (K-pad cols 200..231 are read by MFMA; NaN-safety)
  for (int i = tid; i < 64 * 232; i += 256) { Ad[i] = 0; Ah[i] = 0; }
  __syncthreads();

  // stage deter (fp32 from out) -> bf16 LDS
  for (int idx = tid; idx < 64 * 200; idx += 256) {
    int row = idx / 200, col = idx - row * 200;
    Ad[row * 232 + col] = f2bf(out[((size_t)b * Tn + row) * OUTC + 180 + col]);
  }
  __syncthreads();

  // GEMM1: h = elu(deter @ Wimg + b_img)
  {
    short8 af[7];
#pragma unroll
    for (int kt = 0; kt < 7; ++kt)
      af[kt] = *(const short8*)&Ad[(wv * 16 + lrow) * 232 + kt * 32 + quad * 8];
    for (int nt = 0; nt < 13; ++nt) {
      const short8* bp = Wb + WIMG_8 + (size_t)(nt * 7) * 64 + lane;
      f32x4 acc = z4;
#pragma unroll
      for (int kt = 0; kt < 7; ++kt) acc = MFMA(af[kt], bp[kt * 64], acc);
      int col = nt * 16 + lrow;
      if (col < 200) {
        float bias = b_img[col];
#pragma unroll
        for (int r = 0; r < 4; ++r)
          Ah[(wv * 16 + quad * 4 + r) * 232 + col] = f2bf(elu1(acc[r] + bias));
      }
    }
  }
  __syncthreads();

  // GEMM2: st = h @ Wims + b_ims
  {
    short8 ah[7];
#pragma unroll
    for (int kt = 0; kt < 7; ++kt)
      ah[kt] = *(const short8*)&Ah[(wv * 16 + lrow) * 232 + kt * 32 + quad * 8];
#pragma unroll
    for (int nt = 0; nt < 4; ++nt) {
      const short8* bp = Wb + WIMS_8 + (size_t)(nt * 7) * 64 + lane;
      f32x4 acc = z4;
#pragma unroll
      for (int kt = 0; kt < 7; ++kt) acc = MFMA(ah[kt], bp[kt * 64], acc);
      int col = nt * 16 + lrow;
      if (col < 60) {
        float bias = b_ims[col];
#pragma unroll
        for (int r = 0; r < 4; ++r)
          stf[(wv * 16 + quad * 4 + r) * 66 + col] = acc[r] + bias;
      }
    }
  }
  __syncthreads();

  // epilogue: pm/ps/pst
  for (int idx = tid; idx < 64 * 30; idx += 256) {
    int row = idx / 30, s = idx - row * 30;   // row == t
    float pm = stf[row * 66 + s];
    float ps = splus(stf[row * 66 + 30 + s]) + 0.1f;
    float pst = pm + ps * g_np[((size_t)row * 512 + b) * Sn + s];
    size_t ob = ((size_t)b * Tn + row) * OUTC;
    __builtin_nontemporal_store(pm,  &out[ob + 90 + s]);
    __builtin_nontemporal_store(ps,  &out[ob + 120 + s]);
    __builtin_nontemporal_store(pst, &out[ob + 150 + s]);
  }
}

extern "C" void kernel_launch(void* const* d_in, const int* in_sizes, int n_in,
                              void* d_out, int out_size, void* d_ws, size_t ws_size,
                              hipStream_t stream) {
  (void)in_sizes; (void)n_in; (void)out_size; (void)ws_size;
  const float* emb    = (const float*)d_in[0];
  const float* action = (const float*)d_in[1];
  const float* ctx    = (const float*)d_in[2];
  const float* np_    = (const float*)d_in[3];
  const float* no_    = (const float*)d_in[4];
  const float* w_inp  = (const float*)d_in[5];
  const float* b_inp  = (const float*)d_in[6];
  const float* w_gru  = (const float*)d_in[7];
  const float* b_gru  = (const float*)d_in[8];
  const float* w_img  = (const float*)d_in[9];
  const float* b_img  = (const float*)d_in[10];
  const float* w_obs  = (const float*)d_in[11];
  const float* b_obs  = (const float*)d_in[12];
  const float* w_ims  = (const float*)d_in[13];
  const float* b_ims  = (const float*)d_in[14];
  const float* w_obss = (const float*)d_in[15];
  const float* b_obss = (const float*)d_in[16];

  u16* wsu = (u16*)d_ws;
  float* out = (float*)d_out;

  k_pack2<<<112, 256, 0, stream>>>(w_inp, w_gru, w_img, w_obs, w_ims, w_obss, wsu);
  k_pre<<<512, 256, 0, stream>>>(emb, ctx, action, b_obs, b_inp, wsu);
  k_scan<<<32, 640, 0, stream>>>(no_, b_gru, b_obss, wsu, out);
  k_prior<<<512, 256, 0, stream>>>(np_, b_img, b_ims, wsu, out);
}

// Round 5
// 1213.074 us; speedup vs baseline: 1.5162x; 1.5162x over previous
//
#include <hip/hip_runtime.h>
#include <cstddef>

typedef short short8 __attribute__((ext_vector_type(8)));
typedef float f32x4 __attribute__((ext_vector_type(4)));
typedef unsigned short u16;

// problem dims
#define Bn 512
#define Tn 64
#define En 1024
#define An 32
#define Sn 30
#define Dn 200
#define SSn 230
#define OUTC 380

// packed weight regions, u16 element offsets inside d_ws
#define U16_WINP0  0
#define U16_WINPCA 6656
#define U16_WGRU   66560
#define U16_WIMG   326144
#define U16_WOBSD  372736
#define U16_WIMS   419328
#define U16_WOBSS  433664
#define U16_WOBSE  448000
#define U16_PREO   660992      // pre_obs bf16 [T*B,200]  (b_obs folded)
#define U16_PREI   7214592     // pre_inp bf16 [T*B,200]  (b_inp folded)

// short8 indices (u16/8)
#define WINP0_8  0
#define WINPCA_8 832
#define WGRU_8   8320
#define WIMG_8   40768
#define WOBSD_8  46592
#define WIMS_8   52416
#define WOBSS_8  54208
#define WOBSE_8  56000

#define DEV static __device__ __forceinline__
#define MFMA(a,b,c) __builtin_amdgcn_mfma_f32_16x16x32_bf16((a),(b),(c),0,0,0)

DEV u16 f2bf(float f) {
  union { float f; unsigned u; } v; v.f = f;
  return (u16)((v.u + 0x7FFFu + ((v.u >> 16) & 1u)) >> 16);
}
DEV float bf2f(u16 h) {
  union { unsigned u; float f; } v; v.u = ((unsigned)h) << 16; return v.f;
}
// fast native transcendentals (v_exp_f32 / v_log_f32 / v_rcp_f32)
DEV float fexp(float x)  { return __builtin_amdgcn_exp2f(x * 1.44269504f); }
DEV float sigm(float x)  { return __builtin_amdgcn_rcpf(1.f + fexp(-x)); }
DEV float tanhf_(float x){ return 1.f - 2.f * __builtin_amdgcn_rcpf(fexp(2.f * x) + 1.f); }
DEV float elu1(float x)  { return x > 0.f ? x : fexp(x) - 1.f; }
DEV float splus(float x) { return 0.69314718f * __builtin_amdgcn_logf(1.f + fexp(x)); }

// LDS-only barrier: drains ds ops (cross-wave LDS visibility) but leaves
// global loads/stores in flight across the barrier.
DEV void barx() {
  asm volatile("s_waitcnt lgkmcnt(0)" ::: "memory");
  __builtin_amdgcn_s_barrier();
  asm volatile("" ::: "memory");
}

// ---------------------------------------------------------------- pack kernel
// One block per (region, nt) strip; LDS-staged, coalesced reads along rows.
// B-fragment order: frag (nt*KT+kt): el[lane*8+j] = W[kt*32+(lane>>4)*8+j][nt*16+(lane&15)]
__global__ __launch_bounds__(256) void k_pack2(
    const float* __restrict__ w_inp, const float* __restrict__ w_gru,
    const float* __restrict__ w_img, const float* __restrict__ w_obs,
    const float* __restrict__ w_ims, const float* __restrict__ w_obss,
    u16* __restrict__ ws) {
  int s = blockIdx.x;
  const float* src; int KT, Kr, ldN, roff, colbase, cmax; size_t dstbase; int ntKT;
  if (s < 13)      { src=w_inp;  KT=1;  Kr=30;   ldN=200; roff=0;   int nt=s;    colbase=nt*16; cmax=min(16,200-colbase); dstbase=U16_WINP0;  ntKT=nt*KT; }
  else if (s < 26) { src=w_inp;  KT=9;  Kr=262;  ldN=200; roff=30;  int nt=s-13; colbase=nt*16; cmax=min(16,200-colbase); dstbase=U16_WINPCA; ntKT=nt*KT; }
  else if (s < 65) { src=w_gru;  KT=13; Kr=400;  ldN=600; roff=0;   int ntp=s-26; int g=ntp/3, p=ntp%3;
                     colbase=p*200+g*16; cmax=min(16,200-g*16); dstbase=U16_WGRU; ntKT=ntp*KT; }
  else if (s < 78) { src=w_img;  KT=7;  Kr=200;  ldN=200; roff=0;   int nt=s-65; colbase=nt*16; cmax=min(16,200-colbase); dstbase=U16_WIMG;  ntKT=nt*KT; }
  else if (s < 91) { src=w_obs;  KT=7;  Kr=200;  ldN=200; roff=0;   int nt=s-78; colbase=nt*16; cmax=min(16,200-colbase); dstbase=U16_WOBSD; ntKT=nt*KT; }
  else if (s < 95) { src=w_ims;  KT=7;  Kr=200;  ldN=60;  roff=0;   int nt=s-91; colbase=nt*16; cmax=min(16,60-colbase);  dstbase=U16_WIMS;  ntKT=nt*KT; }
  else if (s < 99) { src=w_obss; KT=7;  Kr=200;  ldN=60;  roff=0;   int nt=s-95; colbase=nt*16; cmax=min(16,60-colbase);  dstbase=U16_WOBSS; ntKT=nt*KT; }
  else             { src=w_obs;  KT=32; Kr=1024; ldN=200; roff=200; int nt=s-99; colbase=nt*16; cmax=min(16,200-colbase); dstbase=U16_WOBSE; ntKT=nt*KT; }

  __shared__ float Ws[2048];       // 128 k-rows x 16 cols
  int tid = threadIdx.x;
  int nchunk = (KT + 3) >> 2;
  for (int kc = 0; kc < nchunk; ++kc) {
    __syncthreads();
    for (int i = tid; i < 2048; i += 256) {
      int r = i >> 4, c = i & 15;
      int k = kc * 128 + r;
      Ws[i] = (k < Kr && c < cmax) ? src[(size_t)(roff + k) * ldN + colbase + c] : 0.f;
    }
    __syncthreads();
    int nf = KT - kc * 4; if (nf > 4) nf = 4;
    int fi = tid >> 6, lane = tid & 63;
    if (fi < nf) {
      int kt = kc * 4 + fi;
      union { u16 h[8]; short8 v; } pk;
#pragma unroll
      for (int j = 0; j < 8; ++j)
        pk.h[j] = f2bf(Ws[(fi * 32 + ((lane >> 4) << 3) + j) * 16 + (lane & 15)]);
      *(short8*)&ws[dstbase + (size_t)(ntKT + kt) * 512 + lane * 8] = pk.v;
    }
  }
}

// ---------------------------------------------------------------- pre kernel
// pre_obs[t*512+b][n] = emb[b][t][:]@Wobse + b_obs    (bf16)
// pre_inp[t*512+b][n] = [ctx|act][b][t][:]@Winpca + b_inp  (bf16)
__global__ __launch_bounds__(256) void k_pre(
    const float* __restrict__ emb, const float* __restrict__ ctx,
    const float* __restrict__ act, const float* __restrict__ b_obs,
    const float* __restrict__ b_inp, u16* __restrict__ ws) {
  __shared__ u16 Asm[64 * 72];
  __shared__ short8 Bsm[26 * 64];
  const short8* Wb = (const short8*)ws;
  u16* preO = ws + U16_PREO;
  u16* preI = ws + U16_PREI;

  int tid = threadIdx.x, wv = tid >> 6, lane = tid & 63;
  int lrow = lane & 15, quad = lane >> 4;
  int m0 = blockIdx.x * 64;
  int t = m0 >> 9, b0 = m0 & 511;

  const f32x4 z4 = {0.f, 0.f, 0.f, 0.f};
  f32x4 acc[13];

  // ---------------- job 1: obs (K=1024 from emb)
#pragma unroll
  for (int i = 0; i < 13; ++i) acc[i] = z4;
  for (int kc = 0; kc < 16; ++kc) {
    __syncthreads();
#pragma unroll
    for (int q = 0; q < 4; ++q) {
      int i = tid + q * 256;
      int row = i >> 4, c4 = i & 15;
      const float* src = emb + ((size_t)((b0 + row) * Tn + t)) * En + kc * 64 + c4 * 4;
      float4 v = *(const float4*)src;
      union { u16 h[4]; unsigned long long ll; } p;
      p.h[0] = f2bf(v.x); p.h[1] = f2bf(v.y); p.h[2] = f2bf(v.z); p.h[3] = f2bf(v.w);
      *(unsigned long long*)&Asm[row * 72 + c4 * 4] = p.ll;
    }
    for (int q = 0; q < 7; ++q) {
      int i = tid + q * 256;
      if (i < 1664) {
        int pair = i >> 6, l = i & 63;
        int ktl = pair / 13, nt = pair % 13;
        Bsm[i] = Wb[WOBSE_8 + (size_t)(nt * 32 + kc * 2 + ktl) * 64 + l];
      }
    }
    __syncthreads();
#pragma unroll
    for (int ktl = 0; ktl < 2; ++ktl) {
      short8 a = *(const short8*)&Asm[(wv * 16 + lrow) * 72 + ktl * 32 + quad * 8];
#pragma unroll
      for (int nt = 0; nt < 13; ++nt)
        acc[nt] = MFMA(a, Bsm[(ktl * 13 + nt) * 64 + lane], acc[nt]);
    }
  }
#pragma unroll
  for (int nt = 0; nt < 13; ++nt) {
    int col = nt * 16 + lrow;
    if (col < 200) {
      float bias = b_obs[col];
#pragma unroll
      for (int r = 0; r < 4; ++r) {
        int m = t * 512 + b0 + wv * 16 + quad * 4 + r;
        preO[(size_t)m * 200 + col] = f2bf(acc[nt][r] + bias);
      }
    }
  }

  // ---------------- job 2: inp (K=262 from [ctx|act])
#pragma unroll
  for (int i = 0; i < 13; ++i) acc[i] = z4;
  for (int kc = 0; kc < 5; ++kc) {
    __syncthreads();
#pragma unroll
    for (int q = 0; q < 4; ++q) {
      int i = tid + q * 256;
      int row = i >> 4, c4 = i & 15;
      union { u16 h[4]; unsigned long long ll; } p;
#pragma unroll
      for (int e = 0; e < 4; ++e) {
        int k = kc * 64 + c4 * 4 + e;
        float v = 0.f;
        if (k < 230)      v = ctx[((size_t)(b0 + row) * Tn + t) * SSn + k];
        else if (k < 262) v = act[((size_t)(b0 + row) * Tn + t) * An + (k - 230)];
        p.h[e] = f2bf(v);
      }
      *(unsigned long long*)&Asm[row * 72 + c4 * 4] = p.ll;
    }
    int nktl = (kc < 4) ? 2 : 1;
    for (int q = 0; q < 7; ++q) {
      int i = tid + q * 256;
      if (i < nktl * 13 * 64) {
        int pair = i >> 6, l = i & 63;
        int ktl = pair / 13, nt = pair % 13;
        Bsm[i] = Wb[WINPCA_8 + (size_t)(nt * 9 + kc * 2 + ktl) * 64 + l];
      }
    }
    __syncthreads();
    for (int ktl = 0; ktl < nktl; ++ktl) {
      short8 a = *(const short8*)&Asm[(wv * 16 + lrow) * 72 + ktl * 32 + quad * 8];
#pragma unroll
      for (int nt = 0; nt < 13; ++nt)
        acc[nt] = MFMA(a, Bsm[(ktl * 13 + nt) * 64 + lane], acc[nt]);
    }
  }
#pragma unroll
  for (int nt = 0; nt < 13; ++nt) {
    int col = nt * 16 + lrow;
    if (col < 200) {
      float bias = b_inp[col];
#pragma unroll
      for (int r = 0; r < 4; ++r) {
        int m = t * 512 + b0 + wv * 16 + quad * 4 + r;
        preI[(size_t)m * 200 + col] = f2bf(acc[nt][r] + bias);
      }
    }
  }
}

// ---------------------------------------------------------------- scan kernel
// 32 blocks x 512 threads (8 waves); block owns 16 batch rows, 64 steps.
// v5: pipelined GRU K-split. The GRU A-operand spans [x_t(0..199) |
//     deter_{t-1}(200..399) | pad] contiguously at parity base pb. K-slices
//     kt=7..12 touch ONLY deter rows -> compute them for step t+1 during the
//     C-phase of step t (right after deter_t lands), carrying ar/ac/au in
//     VGPRs across barriers. Stage B keeps only kt=0..6 + fusion. This
//     splits the 507 KB/step GRU weight streaming ~46/54 across two phases
//     (C-phase was previously idle of global traffic) and shortens B's
//     dependent-MFMA chain 13 -> 7.
//     Wobsd LDS-resident (stage C ds_read-only), Wobss register-resident,
//     relaxed barriers (r3 structure).
__global__ __launch_bounds__(512, 1) void k_scan(
    const float* __restrict__ g_no, const float* __restrict__ b_gru,
    const float* __restrict__ b_obss, const u16* __restrict__ ws,
    float* __restrict__ out) {

  // AB row layout (u16, stride 872): parity p at p*424: [x 0..199 | deter 200..423]
  __shared__ u16 AB[16 * 872];
  __shared__ u16 Uin[16 * 40];      // stoch (cols 0..29; 30,31 multiply zero B rows)
  __shared__ u16 hoA[16 * 232];     // ho; cols 200..231 MUST stay zero (K-pads)
  __shared__ u16 WdL[91 * 512];     // Wobsd: 91 B-fragments, LDS-resident

  const short8* Wb = (const short8*)ws;
  const u16* preO = ws + U16_PREO;
  const u16* preI = ws + U16_PREI;

  const int tid = threadIdx.x, wv = tid >> 6, lane = tid & 63;
  const int lrow = lane & 15, quad = lane >> 4;
  const int b0 = blockIdx.x * 16;
  const f32x4 z4 = {0.f, 0.f, 0.f, 0.f};

  // roles
  const bool two = wv < 5;               // waves 0-4 take a second tile (idx wv+8)
  const int g1 = two ? (wv + 8) : wv;    // second-tile index (self for waves 5-7)
  const int colA0 = wv * 16 + lrow;
  const int colA1 = g1 * 16 + lrow;
  const int dcol0 = colA0;
  const int dcol1 = colA1;
  const int nrow = tid / 30, ns = tid - nrow * 30;   // epilogue role (tid<480)

  // park stage-A fragments
  short8 fA0 = Wb[WINP0_8 + (size_t)wv * 64 + lane];
  short8 fA1 = Wb[WINP0_8 + (size_t)g1 * 64 + lane];

  // per-role biases (update bias -1 folded into bgu)
  float bgr0 = b_gru[dcol0], bgc0 = b_gru[200 + dcol0], bgu0 = b_gru[400 + dcol0] - 1.f;
  float bgr1 = 0.f, bgc1 = 0.f, bgu1 = -1.f;
  if (two && dcol1 < 200) { bgr1 = b_gru[dcol1]; bgc1 = b_gru[200 + dcol1]; bgu1 = b_gru[400 + dcol1] - 1.f; }
  const int cD = (wv & 3) * 16 + lrow;
  const float bD = (wv < 4 && cD < 60) ? b_obss[cD] : 0.f;

  // loop-invariant weight pointers (GRU streams from L2)
  const short8* pr0 = Wb + WGRU_8 + (size_t)((3 * wv + 0) * 13) * 64 + lane;
  const short8* pc0 = Wb + WGRU_8 + (size_t)((3 * wv + 1) * 13) * 64 + lane;
  const short8* pu0 = Wb + WGRU_8 + (size_t)((3 * wv + 2) * 13) * 64 + lane;
  const short8* pr1 = Wb + WGRU_8 + (size_t)((3 * g1 + 0) * 13) * 64 + lane;
  const short8* pc1 = Wb + WGRU_8 + (size_t)((3 * g1 + 1) * 13) * 64 + lane;
  const short8* pu1 = Wb + WGRU_8 + (size_t)((3 * g1 + 2) * 13) * 64 + lane;
  const short8* bpD = Wb + WOBSS_8 + (size_t)(((wv < 4) ? wv : 0) * 7) * 64 + lane;

  // register-resident weights:
  // GRU kt=0,1 for all 6 chains (48 VGPR)
  short8 wR0[2], wC0_[2], wU0[2], wR1[2], wC1_[2], wU1[2];
#pragma unroll
  for (int k = 0; k < 2; ++k) {
    wR0[k] = pr0[k * 64]; wC0_[k] = pc0[k * 64]; wU0[k] = pu0[k * 64];
    wR1[k] = pr1[k * 64]; wC1_[k] = pc1[k * 64]; wU1[k] = pu1[k * 64];
  }
  // Wobss 7 frags (28 VGPR) -> stage D memory-free
  short8 wD[7];
#pragma unroll
  for (int k = 0; k < 7; ++k) wD[k] = bpD[k * 64];

  // stage Wobsd -> LDS (once; 91 KiB, coalesced 16B copies)
  {
    short8* Wl = (short8*)WdL;
    for (int i = tid; i < 91 * 64; i += 512) Wl[i] = Wb[WOBSD_8 + i];
  }

  // zero init ALL carry/pad regions (NaN-safety: MFMA propagates NaN*0)
  for (int i = tid; i < 16 * 872; i += 512) AB[i] = 0;
  for (int i = tid; i < 16 * 40; i += 512) Uin[i] = 0;
  for (int i = tid; i < 16 * 232; i += 512) hoA[i] = 0;
  __syncthreads();

  // sto overlay: f32 view of AB; step t's sto lives in the idle-parity x-region
  float* stoF = (float*)AB;        // row stride 436 floats

  // prefetch step 0 inputs
  u16 pinC0[4], pinC1[4] = {0,0,0,0}, pobC0[4], pobC1[4] = {0,0,0,0};
  float vnoC = 0.f;
  {
    size_t mb = (size_t)b0 + quad * 4;
#pragma unroll
    for (int r = 0; r < 4; ++r) pinC0[r] = preI[(mb + r) * 200 + colA0];
#pragma unroll
    for (int r = 0; r < 4; ++r) pobC0[r] = preO[(mb + r) * 200 + colA0];
    if (two && colA1 < 200) {
#pragma unroll
      for (int r = 0; r < 4; ++r) pinC1[r] = preI[(mb + r) * 200 + colA1];
#pragma unroll
      for (int r = 0; r < 4; ++r) pobC1[r] = preO[(mb + r) * 200 + colA1];
    }
    if (tid < 480) vnoC = g_no[((size_t)b0 + nrow) * Sn + ns];
  }

  // loop-carried gate accumulators; hold the kt=7..12 (deter-half) partial
  // sums computed one step early. deter_{-1}=0 -> start at zero.
  f32x4 ar0 = z4, ac0 = z4, au0 = z4, ar1 = z4, ac1 = z4, au1 = z4;

  for (int t = 0; t < Tn; ++t) {
    const int par = t & 1;
    const int pb = par * 424, qb = 424 - pb;
    const int qbf = qb >> 1;               // sto float offset this step

    barx();   // B1: Uin stoch ready (epilogue of t-1)

    // ---- stage A: x = elu(stoch @ W0 + pre_inp)   [no global loads]
    {
      short8 aU = *(const short8*)&Uin[lrow * 40 + quad * 8];
      f32x4 a0 = MFMA(aU, fA0, z4);
#pragma unroll
      for (int r = 0; r < 4; ++r)
        AB[(quad * 4 + r) * 872 + pb + colA0] = f2bf(elu1(a0[r] + bf2f(pinC0[r])));
      if (two) {
        f32x4 a1 = MFMA(aU, fA1, z4);
        if (colA1 < 200) {
#pragma unroll
          for (int r = 0; r < 4; ++r)
            AB[(quad * 4 + r) * 872 + pb + colA1] = f2bf(elu1(a1[r] + bf2f(pinC1[r])));
        }
      }
    }

    // ---- prefetch inputs for step t+1 (in flight across B2..B1)
    u16 pinN0[4], pinN1[4] = {0,0,0,0}, pobN0[4], pobN1[4] = {0,0,0,0};
    float vnoN = 0.f;
    {
      int tn = (t + 1 < Tn) ? (t + 1) : t;
      size_t mb = (size_t)tn * 512 + b0 + quad * 4;
#pragma unroll
      for (int r = 0; r < 4; ++r) pinN0[r] = preI[(mb + r) * 200 + colA0];
#pragma unroll
      for (int r = 0; r < 4; ++r) pobN0[r] = preO[(mb + r) * 200 + colA0];
      if (two && colA1 < 200) {
#pragma unroll
        for (int r = 0; r < 4; ++r) pinN1[r] = preI[(mb + r) * 200 + colA1];
#pragma unroll
        for (int r = 0; r < 4; ++r) pobN1[r] = preO[(mb + r) * 200 + colA1];
      }
      if (tid < 480) vnoN = g_no[((size_t)tn * 512 + b0 + nrow) * Sn + ns];
    }

    barx();   // B2: x ready

    // ---- stage Bx: finish gates (kt 0..6, x-part) + fused GRU -> deter qb
    {
      short8 ax[7];
#pragma unroll
      for (int kt = 0; kt < 7; ++kt)
        ax[kt] = *(const short8*)&AB[lrow * 872 + pb + kt * 32 + quad * 8];
      if (two) {
#pragma unroll
        for (int kt = 0; kt < 7; ++kt) {   // 6 interleaved chains
          short8 br0 = (kt < 2) ? wR0[kt]  : pr0[kt * 64];
          short8 br1 = (kt < 2) ? wR1[kt]  : pr1[kt * 64];
          short8 bc0 = (kt < 2) ? wC0_[kt] : pc0[kt * 64];
          short8 bc1 = (kt < 2) ? wC1_[kt] : pc1[kt * 64];
          short8 bu0 = (kt < 2) ? wU0[kt]  : pu0[kt * 64];
          short8 bu1 = (kt < 2) ? wU1[kt]  : pu1[kt * 64];
          ar0 = MFMA(ax[kt], br0, ar0);
          ar1 = MFMA(ax[kt], br1, ar1);
          ac0 = MFMA(ax[kt], bc0, ac0);
          ac1 = MFMA(ax[kt], bc1, ac1);
          au0 = MFMA(ax[kt], bu0, au0);
          au1 = MFMA(ax[kt], bu1, au1);
        }
      } else {
#pragma unroll
        for (int kt = 0; kt < 7; ++kt) {
          short8 br0 = (kt < 2) ? wR0[kt]  : pr0[kt * 64];
          short8 bc0 = (kt < 2) ? wC0_[kt] : pc0[kt * 64];
          short8 bu0 = (kt < 2) ? wU0[kt]  : pu0[kt * 64];
          ar0 = MFMA(ax[kt], br0, ar0);
          ac0 = MFMA(ax[kt], bc0, ac0);
          au0 = MFMA(ax[kt], bu0, au0);
        }
      }
#pragma unroll
      for (int r = 0; r < 4; ++r) {
        int row = quad * 4 + r;
        float dold = bf2f(AB[row * 872 + pb + 200 + dcol0]);
        float rs = sigm(ar0[r] + bgr0);
        float cnd = tanhf_(rs * (ac0[r] + bgc0));
        float up = sigm(au0[r] + bgu0);
        float dn = up * cnd + (1.f - up) * dold;
        AB[row * 872 + qb + 200 + dcol0] = f2bf(dn);
        __builtin_nontemporal_store(dn, &out[((size_t)(b0 + row) * Tn + t) * OUTC + 180 + dcol0]);
      }
      if (two && dcol1 < 200) {
#pragma unroll
        for (int r = 0; r < 4; ++r) {
          int row = quad * 4 + r;
          float dold = bf2f(AB[row * 872 + pb + 200 + dcol1]);
          float rs = sigm(ar1[r] + bgr1);
          float cnd = tanhf_(rs * (ac1[r] + bgc1));
          float up = sigm(au1[r] + bgu1);
          float dn = up * cnd + (1.f - up) * dold;
          AB[row * 872 + qb + 200 + dcol1] = f2bf(dn);
          __builtin_nontemporal_store(dn, &out[((size_t)(b0 + row) * Tn + t) * OUTC + 180 + dcol1]);
        }
      }
      // reset for next step's early (deter) half
      ar0 = z4; ac0 = z4; au0 = z4; ar1 = z4; ac1 = z4; au1 = z4;
    }

    barx();   // B3: deter_new ready

    // ---- stage C: ho = elu(deter_new @ Wobsd + pre_obs)   [LDS weights only]
    {
      short8 ad[7];
#pragma unroll
      for (int kt = 0; kt < 7; ++kt)
        ad[kt] = *(const short8*)&AB[lrow * 872 + qb + 200 + kt * 32 + quad * 8];
      f32x4 h0 = z4, h1 = z4;
      if (two) {
#pragma unroll
        for (int kt = 0; kt < 7; ++kt) {
          h0 = MFMA(ad[kt], *(const short8*)&WdL[(wv * 7 + kt) * 512 + lane * 8], h0);
          h1 = MFMA(ad[kt], *(const short8*)&WdL[(g1 * 7 + kt) * 512 + lane * 8], h1);
        }
      } else {
#pragma unroll
        for (int kt = 0; kt < 7; ++kt)
          h0 = MFMA(ad[kt], *(const short8*)&WdL[(wv * 7 + kt) * 512 + lane * 8], h0);
      }
#pragma unroll
      for (int r = 0; r < 4; ++r)
        hoA[(quad * 4 + r) * 232 + colA0] = f2bf(elu1(h0[r] + bf2f(pobC0[r])));
      if (two && colA1 < 200) {
#pragma unroll
        for (int r = 0; r < 4; ++r)
          hoA[(quad * 4 + r) * 232 + colA1] = f2bf(elu1(h1[r] + bf2f(pobC1[r])));
      }
    }

    // ---- stage Bd' (pipelined): kt 7..12 (deter-part) of NEXT step's gates.
    // A-operand rows 224..415 at base qb = deter_t[24..199] + zero pads;
    // deter_t was just written (B3 drained it). Results carried in ar/ac/au.
    {
      short8 axd[6];
#pragma unroll
      for (int kt = 0; kt < 6; ++kt)
        axd[kt] = *(const short8*)&AB[lrow * 872 + qb + (kt + 7) * 32 + quad * 8];
      if (two) {
#pragma unroll
        for (int kt = 0; kt < 6; ++kt) {
          const int k7 = kt + 7;
          ar0 = MFMA(axd[kt], pr0[k7 * 64], ar0);
          ar1 = MFMA(axd[kt], pr1[k7 * 64], ar1);
          ac0 = MFMA(axd[kt], pc0[k7 * 64], ac0);
          ac1 = MFMA(axd[kt], pc1[k7 * 64], ac1);
          au0 = MFMA(axd[kt], pu0[k7 * 64], au0);
          au1 = MFMA(axd[kt], pu1[k7 * 64], au1);
        }
      } else {
#pragma unroll
        for (int kt = 0; kt < 6; ++kt) {
          const int k7 = kt + 7;
          ar0 = MFMA(axd[kt], pr0[k7 * 64], ar0);
          ac0 = MFMA(axd[kt], pc0[k7 * 64], ac0);
          au0 = MFMA(axd[kt], pu0[k7 * 64], au0);
        }
      }
    }

    barx();   // B4: ho ready

    // ---- stage D: so = ho @ Wobss + b  (waves 0-3)   [register weights only]
    if (wv < 4) {
      f32x4 acc = z4;
#pragma unroll
      for (int kt = 0; kt < 7; ++kt) {
        short8 a = *(const short8*)&hoA[lrow * 232 + kt * 32 + quad * 8];
        acc = MFMA(a, wD[kt], acc);
      }
      if (cD < 60) {
#pragma unroll
        for (int r = 0; r < 4; ++r)
          stoF[(quad * 4 + r) * 436 + qbf + cD] = acc[r] + bD;
      }
    }

    barx();   // B5: so ready

    // ---- epilogue: posterior stats + next stoch
    if (tid < 480) {
      size_t ob = ((size_t)(b0 + nrow) * Tn + t) * OUTC;
      float om = stoF[nrow * 436 + qbf + ns];
      float os = splus(stoF[nrow * 436 + qbf + 30 + ns]) + 0.1f;
      float ost = om + os * vnoC;
      __builtin_nontemporal_store(om,  &out[ob + ns]);
      __builtin_nontemporal_store(os,  &out[ob + 30 + ns]);
      __builtin_nontemporal_store(ost, &out[ob + 60 + ns]);
      Uin[nrow * 40 + ns] = f2bf(ost);
    }

    // rotate prefetch registers
#pragma unroll
    for (int r = 0; r < 4; ++r) {
      pinC0[r] = pinN0[r]; pinC1[r] = pinN1[r];
      pobC0[r] = pobN0[r]; pobC1[r] = pobN1[r];
    }
    vnoC = vnoN;
    // loop-top B1 guards Uin/A-region reuse (incl. sto overlay: next A write
    // to the qb x-region happens only after B1 of t+1, past this epilogue)
  }
}

// ---------------------------------------------------------------- prior kernel
// Wide post-pass: h = elu(deter@Wimg+b), st = h@Wims+b, pm/ps/pst -> out[90..180)
__global__ __launch_bounds__(256) void k_prior(
    const float* __restrict__ g_np, const float* __restrict__ b_img,
    const float* __restrict__ b_ims, const u16* __restrict__ ws,
    float* __restrict__ out) {
  __shared__ u16 Ad[64 * 232];
  __shared__ u16 Ah[64 * 232];
  __shared__ float stf[64 * 66];
  const short8* Wb = (const short8*)ws;

  int tid = threadIdx.x, wv = tid >> 6, lane = tid & 63;
  int lrow = lane & 15, quad = lane >> 4;
  int b = blockIdx.x;                 // 64 rows = all t for batch row b
  const f32x4 z4 = {0.f, 0.f, 0.f, 0.f};

  // zero-init (K-pad cols 200..231 are read by MFMA; NaN-safety)
  for (int i = tid; i < 64 * 232; i += 256) { Ad[i] = 0; Ah[i] = 0; }
  __syncthreads();

  // stage deter (fp32 from out) -> bf16 LDS
  for (int idx = tid; idx < 64 * 200; idx += 256) {
    int row = idx / 200, col = idx - row * 200;
    Ad[row * 232 + col] = f2bf(out[((size_t)b * Tn + row) * OUTC + 180 + col]);
  }
  __syncthreads();

  // GEMM1: h = elu(deter @ Wimg + b_img)
  {
    short8 af[7];
#pragma unroll
    for (int kt = 0; kt < 7; ++kt)
      af[kt] = *(const short8*)&Ad[(wv * 16 + lrow) * 232 + kt * 32 + quad * 8];
    for (int nt = 0; nt < 13; ++nt) {
      const short8* bp = Wb + WIMG_8 + (size_t)(nt * 7) * 64 + lane;
      f32x4 acc = z4;
#pragma unroll
      for (int kt = 0; kt < 7; ++kt) acc = MFMA(af[kt], bp[kt * 64], acc);
      int col = nt * 16 + lrow;
      if (col < 200) {
        float bias = b_img[col];
#pragma unroll
        for (int r = 0; r < 4; ++r)
          Ah[(wv * 16 + quad * 4 + r) * 232 + col] = f2bf(elu1(acc[r] + bias));
      }
    }
  }
  __syncthreads();

  // GEMM2: st = h @ Wims + b_ims
  {
    short8 ah[7];
#pragma unroll
    for (int kt = 0; kt < 7; ++kt)
      ah[kt] = *(const short8*)&Ah[(wv * 16 + lrow) * 232 + kt * 32 + quad * 8];
#pragma unroll
    for (int nt = 0; nt < 4; ++nt) {
      const short8* bp = Wb + WIMS_8 + (size_t)(nt * 7) * 64 + lane;
      f32x4 acc = z4;
#pragma unroll
      for (int kt = 0; kt < 7; ++kt) acc = MFMA(ah[kt], bp[kt * 64], acc);
      int col = nt * 16 + lrow;
      if (col < 60) {
        float bias = b_ims[col];
#pragma unroll
        for (int r = 0; r < 4; ++r)
          stf[(wv * 16 + quad * 4 + r) * 66 + col] = acc[r] + bias;
      }
    }
  }
  __syncthreads();

  // epilogue: pm/ps/pst
  for (int idx = tid; idx < 64 * 30; idx += 256) {
    int row = idx / 30, s = idx - row * 30;   // row == t
    float pm = stf[row * 66 + s];
    float ps = splus(stf[row * 66 + 30 + s]) + 0.1f;
    float pst = pm + ps * g_np[((size_t)row * 512 + b) * Sn + s];
    size_t ob = ((size_t)b * Tn + row) * OUTC;
    __builtin_nontemporal_store(pm,  &out[ob + 90 + s]);
    __builtin_nontemporal_store(ps,  &out[ob + 120 + s]);
    __builtin_nontemporal_store(pst, &out[ob + 150 + s]);
  }
}

extern "C" void kernel_launch(void* const* d_in, const int* in_sizes, int n_in,
                              void* d_out, int out_size, void* d_ws, size_t ws_size,
                              hipStream_t stream) {
  (void)in_sizes; (void)n_in; (void)out_size; (void)ws_size;
  const float* emb    = (const float*)d_in[0];
  const float* action = (const float*)d_in[1];
  const float* ctx    = (const float*)d_in[2];
  const float* np_    = (const float*)d_in[3];
  const float* no_    = (const float*)d_in[4];
  const float* w_inp  = (const float*)d_in[5];
  const float* b_inp  = (const float*)d_in[6];
  const float* w_gru  = (const float*)d_in[7];
  const float* b_gru  = (const float*)d_in[8];
  const float* w_img  = (const float*)d_in[9];
  const float* b_img  = (const float*)d_in[10];
  const float* w_obs  = (const float*)d_in[11];
  const float* b_obs  = (const float*)d_in[12];
  const float* w_ims  = (const float*)d_in[13];
  const float* b_ims  = (const float*)d_in[14];
  const float* w_obss = (const float*)d_in[15];
  const float* b_obss = (const float*)d_in[16];

  u16* wsu = (u16*)d_ws;
  float* out = (float*)d_out;

  k_pack2<<<112, 256, 0, stream>>>(w_inp, w_gru, w_img, w_obs, w_ims, w_obss, wsu);
  k_pre<<<512, 256, 0, stream>>>(emb, ctx, action, b_obs, b_inp, wsu);
  k_scan<<<32, 512, 0, stream>>>(no_, b_gru, b_obss, wsu, out);
  k_prior<<<512, 256, 0, stream>>>(np_, b_img, b_ims, wsu, out);
}